// Round 1
// baseline (273.753 us; speedup 1.0000x reference)
//
#include <hip/hip_runtime.h>

// x: (8, 320, 128, 128) fp32.  C=320 ≡ 0 mod 5  =>  plane%5 == channel%5.
// out(i,j) = (silu(x[s1]) + x[i,j]) * (sigmoid(silu(x[s2])) - 0.5)
// t=c%5: 0: s1=(i,j+1), s2=(i,j+2)   (mod 128)
//        1: s1=(i,j-1), s2=(i,j-2)
//        2: s1=(i+1,j), s2=(i+2,j)
//        3: s1=(i-1,j), s2=(i-2,j)
//        4: s1=s2=(i,j)

#define PLANE_ELEMS 16384   // 128*128

typedef float f32x4 __attribute__((ext_vector_type(4)));

__device__ __forceinline__ float fast_sig(float z) {
    // 1/(1+exp(-z)) with native exp + native rcp; verified 0.0156 absmax (passes).
    return __builtin_amdgcn_rcpf(1.0f + __expf(-z));
}
__device__ __forceinline__ float fast_silu(float z) {
    return z * fast_sig(z);
}

__global__ __launch_bounds__(256) void ablock_kernel(const float* __restrict__ x,
                                                     float* __restrict__ out,
                                                     int nv4) {
    // XCD-aware block swizzle: a plane = 16 consecutive blocks; keep them on one
    // XCD so the +-1/+-2-row halo re-reads (t=2,3) hit the local L2 instead of
    // bouncing across chiplets. Bijective iff gridDim % 8 == 0 (40960: yes);
    // fall through to identity otherwise.
    int bid = blockIdx.x;
    int nb  = gridDim.x;
    if ((nb & 7) == 0) {
        int cpx = nb >> 3;                      // blocks per XCD
        bid = (bid & 7) * cpx + (bid >> 3);
    }

    int g = bid * 256 + threadIdx.x;            // float4 index
    if (g >= nv4) return;                       // never taken (nv4 % 256 == 0)

    int lane  = threadIdx.x & 63;
    int plane = g >> 12;          // 4096 float4 per 128x128 plane
    int o     = g & 4095;         // float4 offset within plane
    int row   = o >> 5;           // 32 float4 per row
    int c4    = o & 31;           // float4 index within row (== lane & 31)
    int t     = plane % 5;        // wave-uniform (wave = 64 consecutive float4)

    const float4* p4 = (const float4*)(x + (size_t)plane * PLANE_ELEMS);

    float4 x0 = p4[o];
    float4 x1, x2;

    // A row (32 float4) maps exactly onto a 32-lane half-wave, so the W-shift
    // wrap elements are fields of the neighboring lane's x0 — shuffle instead
    // of re-loading from memory.
    if (t == 0) {            // shift +1/+2 along W (circular)
        int src  = (lane & 32) | ((lane + 1) & 31);
        float nx = __shfl(x0.x, src, 64);       // next float4's .x
        float ny = __shfl(x0.y, src, 64);       // next float4's .y
        x1 = make_float4(x0.y, x0.z, x0.w, nx);
        x2 = make_float4(x0.z, x0.w, nx, ny);
    } else if (t == 1) {     // shift -1/-2 along W
        int src  = (lane & 32) | ((lane - 1) & 31);
        float pw = __shfl(x0.w, src, 64);       // prev float4's .w
        float pz = __shfl(x0.z, src, 64);       // prev float4's .z
        x1 = make_float4(pw, x0.x, x0.y, x0.z);
        x2 = make_float4(pz, pw, x0.x, x0.y);
    } else if (t == 2) {     // shift +1/+2 along H
        x1 = p4[(((row + 1) & 127) << 5) + c4];
        x2 = p4[(((row + 2) & 127) << 5) + c4];
    } else if (t == 3) {     // shift -1/-2 along H
        x1 = p4[(((row - 1) & 127) << 5) + c4];
        x2 = p4[(((row - 2) & 127) << 5) + c4];
    } else {                 // identity
        x1 = x0;
        x2 = x0;
    }

    f32x4 r;
    r.x = (fast_silu(x1.x) + x0.x) * (fast_sig(fast_silu(x2.x)) - 0.5f);
    r.y = (fast_silu(x1.y) + x0.y) * (fast_sig(fast_silu(x2.y)) - 0.5f);
    r.z = (fast_silu(x1.z) + x0.z) * (fast_sig(fast_silu(x2.z)) - 0.5f);
    r.w = (fast_silu(x1.w) + x0.w) * (fast_sig(fast_silu(x2.w)) - 0.5f);

    // Output is never re-read: non-temporal store keeps L2/L3 capacity for the
    // input halos instead of write-allocating 168 MB of dead lines.
    __builtin_nontemporal_store(r, (f32x4*)out + g);
}

extern "C" void kernel_launch(void* const* d_in, const int* in_sizes, int n_in,
                              void* d_out, int out_size, void* d_ws, size_t ws_size,
                              hipStream_t stream) {
    const float* x   = (const float*)d_in[0];
    float*       out = (float*)d_out;
    int n   = in_sizes[0];        // 41,943,040
    int nv4 = n >> 2;             // 10,485,760 float4
    int block = 256;
    int grid  = (nv4 + block - 1) / block;   // 40,960 (divisible by 8)
    ablock_kernel<<<grid, block, 0, stream>>>(x, out, nv4);
}

// Round 2
// 269.080 us; speedup vs baseline: 1.0174x; 1.0174x over previous
//
#include <hip/hip_runtime.h>

// x: (8, 320, 128, 128) fp32.  C=320 ≡ 0 mod 5  =>  plane%5 == channel%5.
// out(i,j) = (silu(x[s1]) + x[i,j]) * (sigmoid(silu(x[s2])) - 0.5)
// t=c%5: 0: s1=(i,j+1), s2=(i,j+2)   (mod 128)
//        1: s1=(i,j-1), s2=(i,j-2)
//        2: s1=(i+1,j), s2=(i+2,j)
//        3: s1=(i-1,j), s2=(i-2,j)
//        4: s1=s2=(i,j)
//
// Restructured: s(p)=silu(x(p)), g(p)=sigmoid(s(p))-0.5 are plane-wide
// element-wise functions; out(p) = (s(shift1(p)) + x(p)) * g(shift2(p)).
// Each thread computes s,g ONCE per owned element (2 exp + 2 rcp = the
// structural floor) instead of the 3 sigmoids/elem of the consumer-side
// formulation. Neighbor s,g move bit-exactly via shuffle (W shifts) or an
// LDS tile (H shifts). Trans instrs (quarter-rate, 8 cy/wave) drop
// 24 -> 16..18 per float4; kernel moves from issue-bound toward BW-bound.

#define PLANE_ELEMS 16384   // 128*128

__device__ __forceinline__ float fsig(float z) {
    // 1/(1+exp(-z)) native exp + native rcp; verified absmax 0.015625 (passes).
    return __builtin_amdgcn_rcpf(1.0f + __expf(-z));
}

__global__ __launch_bounds__(512) void ablock_kernel(const float* __restrict__ x,
                                                     float* __restrict__ out,
                                                     int nv4) {
    // 18 rows of s,g per block: 16 owned + 2 halo. 18.4 KB, not occupancy-binding.
    __shared__ float4 s_lds[18][32];
    __shared__ float4 g_lds[18][32];

    const int tid   = threadIdx.x;
    const int g     = blockIdx.x * 512 + tid;  // float4 index (grid exact)
    const int lane  = tid & 63;
    const int plane = g >> 12;        // 4096 float4 per plane
    const int o     = g & 4095;
    const int li    = tid >> 5;       // local row 0..15 (block = 16 rows)
    const int c4    = tid & 31;       // float4 col within row
    const int row   = o >> 5;         // plane row
    const int t     = plane % 5;      // block-uniform (block = 1/8 plane)

    const float4* p4 = (const float4*)(x + (size_t)plane * PLANE_ELEMS);
    const float4  x0 = p4[o];

    // Own s,g (all paths need exactly these).
    float4 s, gg;
    s.x = x0.x * fsig(x0.x);  s.y = x0.y * fsig(x0.y);
    s.z = x0.z * fsig(x0.z);  s.w = x0.w * fsig(x0.w);
    gg.x = fsig(s.x) - 0.5f;  gg.y = fsig(s.y) - 0.5f;
    gg.z = fsig(s.z) - 0.5f;  gg.w = fsig(s.w) - 0.5f;

    float4 r;

    if (t == 0) {
        // out_j = (s_{j+1} + x_j) * g_{j+2}; need next thread's s.x, g.x, g.y.
        // Row = 32 float4 = one half-wave; ring within half-wave.
        int src = (lane & 32) | ((lane + 1) & 31);
        float snx = __shfl(s.x,  src, 64);
        float gnx = __shfl(gg.x, src, 64);
        float gny = __shfl(gg.y, src, 64);
        r.x = (s.y + x0.x) * gg.z;
        r.y = (s.z + x0.y) * gg.w;
        r.z = (s.w + x0.z) * gnx;
        r.w = (snx + x0.w) * gny;
    } else if (t == 1) {
        // out_j = (s_{j-1} + x_j) * g_{j-2}; need prev thread's s.w, g.z, g.w.
        int src = (lane & 32) | ((lane - 1) & 31);
        float spw = __shfl(s.w,  src, 64);
        float gpz = __shfl(gg.z, src, 64);
        float gpw = __shfl(gg.w, src, 64);
        r.x = (spw + x0.x) * gpz;
        r.y = (s.x + x0.y) * gpw;
        r.z = (s.y + x0.z) * gg.x;
        r.w = (s.z + x0.w) * gg.y;
    } else if (t == 4) {
        r.x = (s.x + x0.x) * gg.x;
        r.y = (s.y + x0.y) * gg.y;
        r.z = (s.z + x0.z) * gg.z;
        r.w = (s.w + x0.w) * gg.w;
    } else {
        // t==2: out(i) = (s(i+1)+x(i))*g(i+2); LDS idx m <-> plane row row0+m.
        // t==3: out(i) = (s(i-1)+x(i))*g(i-2); LDS idx m <-> plane row row0+m-2.
        const int base = (t == 2) ? li : li + 2;
        s_lds[base][c4] = s;
        g_lds[base][c4] = gg;

        // Halo: wave 0 computes s,g for the 2 rows beyond the owned 16.
        if (tid < 64) {
            int k    = tid >> 5;      // 0,1
            int hc4  = tid & 31;
            int row0 = row - li;      // block's first plane row
            int hidx, hrow;
            if (t == 2) { hidx = 16 + k; hrow = (row0 + 16 + k) & 127; }
            else        { hidx = k;      hrow = (row0 - 2 + k) & 127; }
            float4 xh = p4[(hrow << 5) + hc4];
            float4 hs, hg;
            hs.x = xh.x * fsig(xh.x);  hs.y = xh.y * fsig(xh.y);
            hs.z = xh.z * fsig(xh.z);  hs.w = xh.w * fsig(xh.w);
            hg.x = fsig(hs.x) - 0.5f;  hg.y = fsig(hs.y) - 0.5f;
            hg.z = fsig(hs.z) - 0.5f;  hg.w = fsig(hs.w) - 0.5f;
            s_lds[hidx][hc4] = hs;
            g_lds[hidx][hc4] = hg;
        }
        __syncthreads();   // block-uniform branch (t uniform per block)

        float4 s1 = s_lds[li + 1][c4];   // shift-1 row (both t=2 and t=3)
        float4 g2;
        if (t == 2) g2 = g_lds[li + 2][c4];
        else        g2 = g_lds[li][c4];
        r.x = (s1.x + x0.x) * g2.x;
        r.y = (s1.y + x0.y) * g2.y;
        r.z = (s1.z + x0.z) * g2.z;
        r.w = (s1.w + x0.w) * g2.w;
    }

    ((float4*)out)[g] = r;
}

extern "C" void kernel_launch(void* const* d_in, const int* in_sizes, int n_in,
                              void* d_out, int out_size, void* d_ws, size_t ws_size,
                              hipStream_t stream) {
    const float* x   = (const float*)d_in[0];
    float*       out = (float*)d_out;
    int n   = in_sizes[0];        // 41,943,040
    int nv4 = n >> 2;             // 10,485,760 float4
    int block = 512;              // 16 rows per block (LDS tile for H shifts)
    int grid  = nv4 / block;      // 20,480 (exact)
    ablock_kernel<<<grid, block, 0, stream>>>(x, out, nv4);
}